// Round 3
// baseline (109.586 us; speedup 1.0000x reference)
//
#include <hip/hip_runtime.h>
#include <hip/hip_bf16.h>

// Problem: B=8, C=DIM=64, H=W=64 -> pooled 32x32 (N=1024 tokens), 16 heads x d=4.
// R21: pool+qkv+prep fused into ONE kernel; idx u8; full batch->XCD affinity chain.
// R22: (a) attn: 2 of 8 exp2 per inner iter moved trans->VALU via cubic-poly exp2
//          (floor/frac split, exact 2^n scale; rel err ~1e-4 << f16 pack rounding).
//          Trans pipe was the serialization point (64 cy/iter vs VALU 18); new
//          balance trans 48 / VALU ~54 -> ~15% attn cut.
//      (b) proj: 512 blocks (channel halves split) -> 2 blocks/CU, per-thread FMA
//          halved; o re-read doubles but is XCD-local L2.
// ws layout (floats): [unused SEG] | idx[u8, SEG bytes] | q[SEG] | unused | unused
//                     | o[SEG] | kg (2MB) | vg (1.04MB)
// q layout: (B, H=16, N=1024, D=4) contiguous -> per (b,h) a 4096-float slab.

typedef float    f32x4 __attribute__((ext_vector_type(4)));
typedef _Float16 f16x8 __attribute__((ext_vector_type(8)));
typedef unsigned int uint32_tt;

static __device__ __forceinline__ uint32_tt pk2(float a, float b) {   // RTN f16 pair
    uint32_tt lo = (uint32_tt)__builtin_bit_cast(unsigned short, (_Float16)a);
    uint32_tt hi = (uint32_tt)__builtin_bit_cast(unsigned short, (_Float16)b);
    return lo | (hi << 16);
}

// VALU-pipe exp2: n = floor(x), r = x-n, cubic minimax for 2^r on [0,1)
// (max rel err ~1.0e-4), exact 2^n via exponent bits. ~9 VALU ops, zero trans.
static __device__ __forceinline__ float exp2_valu(float x) {
    float n = __builtin_floorf(x);
    float r = x - n;
    float pr = 1.0f + r * (0.695556856f + r * (0.226173572f + r * 0.0781455737f));
    return pr * __builtin_bit_cast(float, ((int)n + 127) << 23);
}

// ---------------- Kernel A (fused): maxpool+argmax -> qkv -> K/V prep ----------------
// grid 512 = 8 batches x 64 16-token tiles; b = p&7 pins batch b to XCD b.
__global__ __launch_bounds__(192) void fused_kernel(const float* __restrict__ x,
                                                    const float* __restrict__ w_qkv,
                                                    float* __restrict__ q,
                                                    uint4* __restrict__ kg,
                                                    uint32_tt* __restrict__ vg,
                                                    unsigned char* __restrict__ idx) {
    __shared__ float trow[16 * 68];                     // pooled tokens
    __shared__ float kx[16 * 68];                       // k exchange (row=key, col=h*4+d)
    __shared__ float vx[16 * 68];                       // v exchange
    int tid = threadIdx.x;                              // 0..191
    int p = blockIdx.x;
    int b = p & 7;                                      // XCD p%8 == b owns batch b
    int tile = p >> 3;                                  // 0..63
    int n0 = tile * 16;
    int hp = n0 >> 5, wp0 = n0 & 31;                    // wp0 in {0,16}

    // weight loads issued first (independent; overlap phase 1)
    int j  = tid % 96;                                  // my column pair {j, j+96}
    int rh = tid / 96;                                  // my row half (8 rows)
    float wc0[64], wc1[64];
    #pragma unroll
    for (int c = 0; c < 64; c++) {
        wc0[c] = w_qkv[c * 192 + j];
        wc1[c] = w_qkv[c * 192 + j + 96];
    }

    // Phase 1: pool (identical math to old pool_kernel)
    for (int i = tid; i < 1024; i += 192) {
        int c = i >> 4, nn = i & 15, wp = wp0 + nn;
        const float* px = x + (((b * 64 + c) * 64 + 2 * hp) * 64 + 2 * wp);
        float2 r0 = *(const float2*)px;
        float2 r1 = *(const float2*)(px + 64);
        float best = r0.x; int bi = 0;                  // first-max semantics (strict >)
        if (r0.y > best) { best = r0.y; bi = 1; }
        if (r1.x > best) { best = r1.x; bi = 2; }
        if (r1.y > best) { best = r1.y; bi = 3; }
        trow[nn * 68 + c] = best;
        idx[((b * 64 + c) * 32 + hp) * 32 + wp] = (unsigned char)bi;
    }
    __syncthreads();

    // Phase 2+3: qkv dots; q -> global, k/v -> LDS exchange
    int s0 = j >> 6, h0 = (j >> 2) & 15, d0 = j & 3;
    int j1 = j + 96;
    int s1 = j1 >> 6;                                   // 1 or 2 (never q)
    int col0 = j & 63, col1 = j1 & 63;
    float* xb0 = (s0 == 1) ? kx : vx;                   // only used when s0 != 0
    float* xb1 = (s1 == 1) ? kx : vx;
    for (int r = 0; r < 8; r++) {
        int row = rh * 8 + r;
        const float4* tr = (const float4*)&trow[row * 68];
        float a0 = 0.f, a1 = 0.f;
        #pragma unroll
        for (int c4 = 0; c4 < 16; c4++) {
            float4 tv = tr[c4];                         // <=2-way LDS broadcast: free
            a0 += tv.x * wc0[c4 * 4] + tv.y * wc0[c4 * 4 + 1]
                + tv.z * wc0[c4 * 4 + 2] + tv.w * wc0[c4 * 4 + 3];
            a1 += tv.x * wc1[c4 * 4] + tv.y * wc1[c4 * 4 + 1]
                + tv.z * wc1[c4 * 4 + 2] + tv.w * wc1[c4 * 4 + 3];
        }
        int n = n0 + row;
        if (s0 == 0) q[((b * 16 + h0) * 1024 + n) * 4 + d0] = a0;
        else         xb0[row * 68 + col0] = a0;
        xb1[row * 68 + col1] = a1;                      // always k or v
    }
    __syncthreads();

    // Phase 4a: kg -- Markidis f16x8 per key, bit-identical to prep_kernel
    for (int e = tid; e < 256; e += 192) {
        int kl = e & 15, h = e >> 4;                    // kl fastest: 256B global runs
        float4 kf = *(const float4*)&kx[kl * 68 + h * 4];
        f16x8 kk;
        kk[0] = (_Float16)kf.x; kk[4] = (_Float16)(kf.x - (float)kk[0]);
        kk[1] = (_Float16)kf.y; kk[5] = (_Float16)(kf.y - (float)kk[1]);
        kk[2] = (_Float16)kf.z; kk[6] = (_Float16)(kf.z - (float)kk[2]);
        kk[3] = (_Float16)kf.w; kk[7] = (_Float16)(kf.w - (float)kk[3]);
        kg[(b * 16 + h) * 1024 + n0 + kl] = __builtin_bit_cast(uint4, kk);
    }
    // Phase 4b: vg -- kappa-permuted u32 pairs (pos(key+1)=pos(key)+1 for even key)
    int b4 = (n0 >> 4) & 1;
    int pwbase = ((n0 & ~31) >> 1) + (b4 << 1);
    for (int e = tid; e < 512; e += 192) {
        int m = e & 7, h = (e >> 3) & 15, d = e >> 7;
        float v0 = vx[(2 * m) * 68 + h * 4 + d];
        float v1 = vx[(2 * m + 1) * 68 + h * 4 + d];
        int pw = pwbase + ((m >> 1) << 2) + (m & 1);
        vg[(b * 16 + h) * 2080 + d * 520 + pw] = pk2(v0, v1);
    }
}

// ---------------- Kernel C: dual-MFMA attention, 32-key tile-pairs ------------------
// R19-frozen scheme; R22: p03/p13 computed on VALU (cubic exp2) to relieve the
// saturated trans pipe (64 -> 48 cy/iter trans, VALU 18 -> ~54).
//  MFMA1: S^T-14 = K x Q^T + C(-14). MFMA2: O^T = V^T x P^T, ones-row m=4 gives l.
// grid = 128 bh * 8 row-blocks of 128; R20 bijection: all 8 rb of a bh on ONE XCD.
__global__ __launch_bounds__(256, 4) void attn_kernel(const float* __restrict__ q,
                                                      const uint4* __restrict__ kg,
                                                      const uint32_tt* __restrict__ vg,
                                                      float* __restrict__ o) {
    __shared__ __align__(16) unsigned char smem[27840];
    f16x8* Kh2 = (f16x8*)smem;                          // [0,16384): 1024 keys {hi4|lo4}
    // VTu rows at smem+16384, stride 2080 B; rows 0-3 copied, row 4 = ones (local)
    float* lsc = (float*)(smem + 26752);                // l exchange (1 KB)
    int p = blockIdx.x;                                 // 1024 blocks
    int xcd = p & 7, slot = p >> 3;                     // XCD-local decomposition
    int bh = (xcd << 4) | (slot >> 3);                  // all 8 rb of bh: same p%8
    int row0 = (slot & 7) * 128;
    int tid = threadIdx.x;
    uint4* smem4 = (uint4*)smem;
    const uint4* kgb = kg + bh * 1024;
    const uint4* vgb = (const uint4*)(vg + bh * 2080);
    #pragma unroll
    for (int i = 0; i < 4; i++)                         // K: 16 KB raw copy
        smem4[i * 256 + tid] = kgb[i * 256 + tid];
    #pragma unroll
    for (int i = 0; i < 3; i++) {                       // V rows 0-3: 8320 B raw copy
        int ix = i * 256 + tid;
        if (ix < 520) smem4[1024 + ix] = vgb[ix];
    }
    {                                                   // ones row: 2 KB of f16 1.0
        uint32_tt* op = (uint32_tt*)(smem + 24704);
        op[tid] = 0x3C003C00u;
        op[256 + tid] = 0x3C003C00u;
    }
    int w = tid >> 6, lane = tid & 63;
    int c = lane & 15, quad = lane >> 4;
    int mv = (c < 5) ? c : 4;                           // clamp -> broadcast ones-row
    const float C1 = 0.5f * 1.44269504088896f;          // scale*log2(e), folded into Q
    const float4* qp4 = (const float4*)(q + bh * 4096);
    f16x8 bq[2];
    #pragma unroll
    for (int s = 0; s < 2; s++) {                       // Q Markidis B-frags (2 strips)
        int rowg = row0 + w * 32 + s * 16 + c;
        float4 qv = qp4[rowg];
        float qx = qv.x * C1, qy = qv.y * C1, qz = qv.z * C1, qw = qv.w * C1;
        _Float16 hx = (_Float16)qx, hy = (_Float16)qy,
                 hz = (_Float16)qz, hw = (_Float16)qw;
        _Float16 gx = (_Float16)(qx - (float)hx), gy = (_Float16)(qy - (float)hy),
                 gz = (_Float16)(qz - (float)hz), gw = (_Float16)(qw - (float)hw);
        f16x8 a = {};
        if (quad == 0) {
            a[0] = hx; a[1] = hy; a[2] = hz; a[3] = hw;
            a[4] = hx; a[5] = hy; a[6] = hz; a[7] = hw;
        } else if (quad == 1) {
            a[0] = gx; a[1] = gy; a[2] = gz; a[3] = gw;
            a[4] = gx; a[5] = gy; a[6] = gz; a[7] = gw;
        }
        bq[s] = a;
    }
    __syncthreads();
    f32x4 acc[2];
    acc[0] = (f32x4)(0.f); acc[1] = (f32x4)(0.f);
    const f32x4 cm14 = { -14.f, -14.f, -14.f, -14.f }; // shift rides in MFMA1's C
    #pragma unroll 2
    for (int T = 0; T < 32; T++) {                      // 32-key tile-pairs
        f16x8 ka0 = Kh2[(2 * T) * 16 + c];              // ds_read_b128 (broadcast)
        f16x8 ka1 = Kh2[(2 * T + 1) * 16 + c];
        const uint4* vptr = (const uint4*)(smem + 16384
                                           + mv * 2080 + T * 64 + quad * 16);
        f16x8 va = __builtin_bit_cast(f16x8, *vptr);    // V^T A-frag: 32 keys, 1 read
        #pragma unroll
        for (int s = 0; s < 2; s++) {
            f32x4 S0 = __builtin_amdgcn_mfma_f32_16x16x32_f16(ka0, bq[s], cm14, 0, 0, 0);
            f32x4 S1 = __builtin_amdgcn_mfma_f32_16x16x32_f16(ka1, bq[s], cm14, 0, 0, 0);
            float p00 = __builtin_amdgcn_exp2f(S0[0]);  // 6 on trans pipe
            float p01 = __builtin_amdgcn_exp2f(S0[1]);
            float p02 = __builtin_amdgcn_exp2f(S0[2]);
            float p03 = exp2_valu(S0[3]);               // 2 on VALU pipe (R22)
            float p10 = __builtin_amdgcn_exp2f(S1[0]);
            float p11 = __builtin_amdgcn_exp2f(S1[1]);
            float p12 = __builtin_amdgcn_exp2f(S1[2]);
            float p13 = exp2_valu(S1[3]);
            uint4 pbu;                                  // v_cvt_pkrtz: 2 converts/instr
            pbu.x = __builtin_bit_cast(uint32_tt, __builtin_amdgcn_cvt_pkrtz(p00, p01));
            pbu.y = __builtin_bit_cast(uint32_tt, __builtin_amdgcn_cvt_pkrtz(p02, p03));
            pbu.z = __builtin_bit_cast(uint32_tt, __builtin_amdgcn_cvt_pkrtz(p10, p11));
            pbu.w = __builtin_bit_cast(uint32_tt, __builtin_amdgcn_cvt_pkrtz(p12, p13));
            f16x8 pb = __builtin_bit_cast(f16x8, pbu);
            acc[s] = __builtin_amdgcn_mfma_f32_16x16x32_f16(va, pb, acc[s], 0, 0, 0);
        }
    }
    // Epilogue: quad1 reg0 holds l (row 4 = ones-row); quad0 regs 0-3 hold O dims.
    if (quad == 1) {
        #pragma unroll
        for (int s = 0; s < 2; s++) lsc[w * 32 + s * 16 + c] = acc[s][0];
    }
    __syncthreads();
    if (quad == 0) {
        int b0 = bh >> 4, h = bh & 15;
        #pragma unroll
        for (int s = 0; s < 2; s++) {
            float rl = 1.f / lsc[w * 32 + s * 16 + c];
            int rowg = row0 + w * 32 + s * 16 + c;
            float4 res = { acc[s][0] * rl, acc[s][1] * rl,
                           acc[s][2] * rl, acc[s][3] * rl };
            *(float4*)&o[(b0 * 1024 + rowg) * 64 + h * 4] = res;
        }
    }
}

// ---------------- Kernel D: o @ w_proj + BN + max-unpool scatter ----------------
// R22: 512 blocks = (half, hp, b); each block does 32 channels -> 2 blocks/CU,
// per-thread FMA halved (one c-group of 4 per thread). o re-read is XCD-local L2.
__global__ __launch_bounds__(256) void proj_kernel(const float* __restrict__ o,
                                                   const float* __restrict__ w_proj,
                                                   const float* __restrict__ gamma,
                                                   const float* __restrict__ beta,
                                                   const float* __restrict__ mean,
                                                   const float* __restrict__ var,
                                                   const unsigned char* __restrict__ idx,
                                                   float* __restrict__ out) {
    __shared__ float ws32[64 * 32];                     // my 32 columns of w_proj
    int p = blockIdx.x;
    int b = p & 7, hp = (p >> 3) & 31, half = p >> 8;   // XCD b serves batch b
    int tid = threadIdx.x;
    int ch0 = half * 32;
    for (int i = tid; i < 2048; i += 256)
        ws32[i] = w_proj[(i >> 5) * 64 + ch0 + (i & 31)];
    int wp = tid & 31, cg = tid >> 5;                   // 8 c-groups x 32 wp
    float oreg[64];                                     // my o row in registers
    const float* orow = o + (b * 1024 + hp * 32 + wp) * 64;
    #pragma unroll
    for (int a4 = 0; a4 < 16; a4++) {
        float4 t4 = ((const float4*)orow)[a4];
        oreg[a4 * 4] = t4.x; oreg[a4 * 4 + 1] = t4.y;
        oreg[a4 * 4 + 2] = t4.z; oreg[a4 * 4 + 3] = t4.w;
    }
    __syncthreads();
    {
        int cc0 = cg * 4;                               // my 4 columns within half
        float4 acc = {0.f, 0.f, 0.f, 0.f};
        #pragma unroll
        for (int a = 0; a < 64; a++) {
            float4 wv = *(const float4*)&ws32[a * 32 + cc0];  // 2-addr broadcast
            acc.x += oreg[a] * wv.x; acc.y += oreg[a] * wv.y;
            acc.z += oreg[a] * wv.z; acc.w += oreg[a] * wv.w;
        }
        float accs[4] = { acc.x, acc.y, acc.z, acc.w };
        #pragma unroll
        for (int i = 0; i < 4; i++) {
            int c = ch0 + cc0 + i;
            float inv = gamma[c] * rsqrtf(var[c] + 1e-5f);
            float val = accs[i] * inv + (beta[c] - mean[c] * inv);
            int id = idx[((b * 64 + c) * 32 + hp) * 32 + wp];
            int base = ((b * 64 + c) * 64 + 2 * hp) * 64 + 2 * wp;
            float2 r0 = { id == 0 ? val : 0.f, id == 1 ? val : 0.f };
            float2 r1 = { id == 2 ? val : 0.f, id == 3 ? val : 0.f };
            *(float2*)&out[base] = r0;                  // row 2hp,   cols 2wp..2wp+1
            *(float2*)&out[base + 64] = r1;             // row 2hp+1
        }
    }
}

extern "C" void kernel_launch(void* const* d_in, const int* in_sizes, int n_in,
                              void* d_out, int out_size, void* d_ws, size_t ws_size,
                              hipStream_t stream) {
    const float* x      = (const float*)d_in[0];
    const float* w_qkv  = (const float*)d_in[1];
    const float* w_proj = (const float*)d_in[2];
    const float* gamma  = (const float*)d_in[3];
    const float* beta   = (const float*)d_in[4];
    const float* bn_mean= (const float*)d_in[5];
    const float* bn_var = (const float*)d_in[6];
    float* out = (float*)d_out;

    const int SEG = 524288;                             // 8*1024*64
    float* ws = (float*)d_ws;
    unsigned char* idx = (unsigned char*)(ws + SEG);    // u8 (SEG bytes used)
    float* q   = ws + 2 * SEG;
    float* o   = ws + 5 * SEG;
    uint4*     kg = (uint4*)(ws + 6 * SEG);             // 2 MB
    uint32_tt* vg = (uint32_tt*)(ws + 7 * SEG);         // 1.04 MB

    fused_kernel<<<512, 192, 0, stream>>>(x, w_qkv, q, kg, vg, idx);
    attn_kernel<<<1024, 256, 0, stream>>>(q, kg, vg, o);
    proj_kernel<<<512, 256, 0, stream>>>(o, w_proj, gamma, beta, bn_mean, bn_var, idx, out);
}

// Round 4
// 105.012 us; speedup vs baseline: 1.0436x; 1.0436x over previous
//
#include <hip/hip_runtime.h>
#include <hip/hip_bf16.h>

// Problem: B=8, C=DIM=64, H=W=64 -> pooled 32x32 (N=1024 tokens), 16 heads x d=4.
// R21: pool+qkv+prep fused into ONE kernel; idx u8; full batch->XCD affinity chain.
// R22 post-mortem: exp2_valu (2 of 8 exps on VALU) REGRESSED ~+3us -- the 9-op
//   dependent VALU chain added cost; trans-pipe-limiter model unvalidated. REVERTED.
// R23: attn restored to R21-exact (all 8 v_exp_f32). proj keeps the R22 512-block
//   split (2 blocks/CU, per-thread FMA halved) as the single variable under test.
// ws layout (floats): [unused SEG] | idx[u8, SEG bytes] | q[SEG] | unused | unused
//                     | o[SEG] | kg (2MB) | vg (1.04MB)
// q layout: (B, H=16, N=1024, D=4) contiguous -> per (b,h) a 4096-float slab.

typedef float    f32x4 __attribute__((ext_vector_type(4)));
typedef _Float16 f16x8 __attribute__((ext_vector_type(8)));
typedef unsigned int uint32_tt;

static __device__ __forceinline__ uint32_tt pk2(float a, float b) {   // RTN f16 pair
    uint32_tt lo = (uint32_tt)__builtin_bit_cast(unsigned short, (_Float16)a);
    uint32_tt hi = (uint32_tt)__builtin_bit_cast(unsigned short, (_Float16)b);
    return lo | (hi << 16);
}

// ---------------- Kernel A (fused): maxpool+argmax -> qkv -> K/V prep ----------------
// grid 512 = 8 batches x 64 16-token tiles; b = p&7 pins batch b to XCD b.
__global__ __launch_bounds__(192) void fused_kernel(const float* __restrict__ x,
                                                    const float* __restrict__ w_qkv,
                                                    float* __restrict__ q,
                                                    uint4* __restrict__ kg,
                                                    uint32_tt* __restrict__ vg,
                                                    unsigned char* __restrict__ idx) {
    __shared__ float trow[16 * 68];                     // pooled tokens
    __shared__ float kx[16 * 68];                       // k exchange (row=key, col=h*4+d)
    __shared__ float vx[16 * 68];                       // v exchange
    int tid = threadIdx.x;                              // 0..191
    int p = blockIdx.x;
    int b = p & 7;                                      // XCD p%8 == b owns batch b
    int tile = p >> 3;                                  // 0..63
    int n0 = tile * 16;
    int hp = n0 >> 5, wp0 = n0 & 31;                    // wp0 in {0,16}

    // weight loads issued first (independent; overlap phase 1)
    int j  = tid % 96;                                  // my column pair {j, j+96}
    int rh = tid / 96;                                  // my row half (8 rows)
    float wc0[64], wc1[64];
    #pragma unroll
    for (int c = 0; c < 64; c++) {
        wc0[c] = w_qkv[c * 192 + j];
        wc1[c] = w_qkv[c * 192 + j + 96];
    }

    // Phase 1: pool (identical math to old pool_kernel)
    for (int i = tid; i < 1024; i += 192) {
        int c = i >> 4, nn = i & 15, wp = wp0 + nn;
        const float* px = x + (((b * 64 + c) * 64 + 2 * hp) * 64 + 2 * wp);
        float2 r0 = *(const float2*)px;
        float2 r1 = *(const float2*)(px + 64);
        float best = r0.x; int bi = 0;                  // first-max semantics (strict >)
        if (r0.y > best) { best = r0.y; bi = 1; }
        if (r1.x > best) { best = r1.x; bi = 2; }
        if (r1.y > best) { best = r1.y; bi = 3; }
        trow[nn * 68 + c] = best;
        idx[((b * 64 + c) * 32 + hp) * 32 + wp] = (unsigned char)bi;
    }
    __syncthreads();

    // Phase 2+3: qkv dots; q -> global, k/v -> LDS exchange
    int s0 = j >> 6, h0 = (j >> 2) & 15, d0 = j & 3;
    int j1 = j + 96;
    int s1 = j1 >> 6;                                   // 1 or 2 (never q)
    int col0 = j & 63, col1 = j1 & 63;
    float* xb0 = (s0 == 1) ? kx : vx;                   // only used when s0 != 0
    float* xb1 = (s1 == 1) ? kx : vx;
    for (int r = 0; r < 8; r++) {
        int row = rh * 8 + r;
        const float4* tr = (const float4*)&trow[row * 68];
        float a0 = 0.f, a1 = 0.f;
        #pragma unroll
        for (int c4 = 0; c4 < 16; c4++) {
            float4 tv = tr[c4];                         // <=2-way LDS broadcast: free
            a0 += tv.x * wc0[c4 * 4] + tv.y * wc0[c4 * 4 + 1]
                + tv.z * wc0[c4 * 4 + 2] + tv.w * wc0[c4 * 4 + 3];
            a1 += tv.x * wc1[c4 * 4] + tv.y * wc1[c4 * 4 + 1]
                + tv.z * wc1[c4 * 4 + 2] + tv.w * wc1[c4 * 4 + 3];
        }
        int n = n0 + row;
        if (s0 == 0) q[((b * 16 + h0) * 1024 + n) * 4 + d0] = a0;
        else         xb0[row * 68 + col0] = a0;
        xb1[row * 68 + col1] = a1;                      // always k or v
    }
    __syncthreads();

    // Phase 4a: kg -- Markidis f16x8 per key, bit-identical to prep_kernel
    for (int e = tid; e < 256; e += 192) {
        int kl = e & 15, h = e >> 4;                    // kl fastest: 256B global runs
        float4 kf = *(const float4*)&kx[kl * 68 + h * 4];
        f16x8 kk;
        kk[0] = (_Float16)kf.x; kk[4] = (_Float16)(kf.x - (float)kk[0]);
        kk[1] = (_Float16)kf.y; kk[5] = (_Float16)(kf.y - (float)kk[1]);
        kk[2] = (_Float16)kf.z; kk[6] = (_Float16)(kf.z - (float)kk[2]);
        kk[3] = (_Float16)kf.w; kk[7] = (_Float16)(kf.w - (float)kk[3]);
        kg[(b * 16 + h) * 1024 + n0 + kl] = __builtin_bit_cast(uint4, kk);
    }
    // Phase 4b: vg -- kappa-permuted u32 pairs (pos(key+1)=pos(key)+1 for even key)
    int b4 = (n0 >> 4) & 1;
    int pwbase = ((n0 & ~31) >> 1) + (b4 << 1);
    for (int e = tid; e < 512; e += 192) {
        int m = e & 7, h = (e >> 3) & 15, d = e >> 7;
        float v0 = vx[(2 * m) * 68 + h * 4 + d];
        float v1 = vx[(2 * m + 1) * 68 + h * 4 + d];
        int pw = pwbase + ((m >> 1) << 2) + (m & 1);
        vg[(b * 16 + h) * 2080 + d * 520 + pw] = pk2(v0, v1);
    }
}

// ---------------- Kernel C: dual-MFMA attention, 32-key tile-pairs ------------------
// R21-exact (R22's exp2_valu reverted -- it regressed).
//  MFMA1: S^T-14 = K x Q^T + C(-14).  A = {kh|kl} Markidis (lane m=key); B = Q
//         Markidis (quad0={qh|qh}, quad1={ql|ql}) -> fp32-exact S. C row=quad*4+reg.
//  MFMA2: O^T = V^T x P^T over 32 keys/instr: V plain f16, kappa-permuted layout;
//         ones-row m=4 emits l = sum(p); exp2(S-14) cancels in O/l; P via v_cvt_pkrtz.
// grid = 128 bh * 8 row-blocks of 128; R20 bijection: all 8 rb of a bh on ONE XCD.
__global__ __launch_bounds__(256, 4) void attn_kernel(const float* __restrict__ q,
                                                      const uint4* __restrict__ kg,
                                                      const uint32_tt* __restrict__ vg,
                                                      float* __restrict__ o) {
    __shared__ __align__(16) unsigned char smem[27840];
    f16x8* Kh2 = (f16x8*)smem;                          // [0,16384): 1024 keys {hi4|lo4}
    // VTu rows at smem+16384, stride 2080 B; rows 0-3 copied, row 4 = ones (local)
    float* lsc = (float*)(smem + 26752);                // l exchange (1 KB)
    int p = blockIdx.x;                                 // 1024 blocks
    int xcd = p & 7, slot = p >> 3;                     // XCD-local decomposition
    int bh = (xcd << 4) | (slot >> 3);                  // all 8 rb of bh: same p%8
    int row0 = (slot & 7) * 128;
    int tid = threadIdx.x;
    uint4* smem4 = (uint4*)smem;
    const uint4* kgb = kg + bh * 1024;
    const uint4* vgb = (const uint4*)(vg + bh * 2080);
    #pragma unroll
    for (int i = 0; i < 4; i++)                         // K: 16 KB raw copy
        smem4[i * 256 + tid] = kgb[i * 256 + tid];
    #pragma unroll
    for (int i = 0; i < 3; i++) {                       // V rows 0-3: 8320 B raw copy
        int ix = i * 256 + tid;
        if (ix < 520) smem4[1024 + ix] = vgb[ix];
    }
    {                                                   // ones row: 2 KB of f16 1.0
        uint32_tt* op = (uint32_tt*)(smem + 24704);
        op[tid] = 0x3C003C00u;
        op[256 + tid] = 0x3C003C00u;
    }
    int w = tid >> 6, lane = tid & 63;
    int c = lane & 15, quad = lane >> 4;
    int mv = (c < 5) ? c : 4;                           // clamp -> broadcast ones-row
    const float C1 = 0.5f * 1.44269504088896f;          // scale*log2(e), folded into Q
    const float4* qp4 = (const float4*)(q + bh * 4096);
    f16x8 bq[2];
    #pragma unroll
    for (int s = 0; s < 2; s++) {                       // Q Markidis B-frags (2 strips)
        int rowg = row0 + w * 32 + s * 16 + c;
        float4 qv = qp4[rowg];
        float qx = qv.x * C1, qy = qv.y * C1, qz = qv.z * C1, qw = qv.w * C1;
        _Float16 hx = (_Float16)qx, hy = (_Float16)qy,
                 hz = (_Float16)qz, hw = (_Float16)qw;
        _Float16 gx = (_Float16)(qx - (float)hx), gy = (_Float16)(qy - (float)hy),
                 gz = (_Float16)(qz - (float)hz), gw = (_Float16)(qw - (float)hw);
        f16x8 a = {};
        if (quad == 0) {
            a[0] = hx; a[1] = hy; a[2] = hz; a[3] = hw;
            a[4] = hx; a[5] = hy; a[6] = hz; a[7] = hw;
        } else if (quad == 1) {
            a[0] = gx; a[1] = gy; a[2] = gz; a[3] = gw;
            a[4] = gx; a[5] = gy; a[6] = gz; a[7] = gw;
        }
        bq[s] = a;
    }
    __syncthreads();
    f32x4 acc[2];
    acc[0] = (f32x4)(0.f); acc[1] = (f32x4)(0.f);
    const f32x4 cm14 = { -14.f, -14.f, -14.f, -14.f }; // shift rides in MFMA1's C
    #pragma unroll 2
    for (int T = 0; T < 32; T++) {                      // 32-key tile-pairs
        f16x8 ka0 = Kh2[(2 * T) * 16 + c];              // ds_read_b128 (broadcast)
        f16x8 ka1 = Kh2[(2 * T + 1) * 16 + c];
        const uint4* vptr = (const uint4*)(smem + 16384
                                           + mv * 2080 + T * 64 + quad * 16);
        f16x8 va = __builtin_bit_cast(f16x8, *vptr);    // V^T A-frag: 32 keys, 1 read
        #pragma unroll
        for (int s = 0; s < 2; s++) {
            f32x4 S0 = __builtin_amdgcn_mfma_f32_16x16x32_f16(ka0, bq[s], cm14, 0, 0, 0);
            f32x4 S1 = __builtin_amdgcn_mfma_f32_16x16x32_f16(ka1, bq[s], cm14, 0, 0, 0);
            float p00 = __builtin_amdgcn_exp2f(S0[0]);  // bare v_exp_f32 (trans pipe)
            float p01 = __builtin_amdgcn_exp2f(S0[1]);
            float p02 = __builtin_amdgcn_exp2f(S0[2]);
            float p03 = __builtin_amdgcn_exp2f(S0[3]);
            float p10 = __builtin_amdgcn_exp2f(S1[0]);
            float p11 = __builtin_amdgcn_exp2f(S1[1]);
            float p12 = __builtin_amdgcn_exp2f(S1[2]);
            float p13 = __builtin_amdgcn_exp2f(S1[3]);
            uint4 pbu;                                  // v_cvt_pkrtz: 2 converts/instr
            pbu.x = __builtin_bit_cast(uint32_tt, __builtin_amdgcn_cvt_pkrtz(p00, p01));
            pbu.y = __builtin_bit_cast(uint32_tt, __builtin_amdgcn_cvt_pkrtz(p02, p03));
            pbu.z = __builtin_bit_cast(uint32_tt, __builtin_amdgcn_cvt_pkrtz(p10, p11));
            pbu.w = __builtin_bit_cast(uint32_tt, __builtin_amdgcn_cvt_pkrtz(p12, p13));
            f16x8 pb = __builtin_bit_cast(f16x8, pbu);
            acc[s] = __builtin_amdgcn_mfma_f32_16x16x32_f16(va, pb, acc[s], 0, 0, 0);
        }
    }
    // Epilogue: quad1 reg0 holds l (row 4 = ones-row); quad0 regs 0-3 hold O dims.
    if (quad == 1) {
        #pragma unroll
        for (int s = 0; s < 2; s++) lsc[w * 32 + s * 16 + c] = acc[s][0];
    }
    __syncthreads();
    if (quad == 0) {
        int b0 = bh >> 4, h = bh & 15;
        #pragma unroll
        for (int s = 0; s < 2; s++) {
            float rl = 1.f / lsc[w * 32 + s * 16 + c];
            int rowg = row0 + w * 32 + s * 16 + c;
            float4 res = { acc[s][0] * rl, acc[s][1] * rl,
                           acc[s][2] * rl, acc[s][3] * rl };
            *(float4*)&o[(b0 * 1024 + rowg) * 64 + h * 4] = res;
        }
    }
}

// ---------------- Kernel D: o @ w_proj + BN + max-unpool scatter ----------------
// R22 variant under test (single variable vs R21): 512 blocks = (half, hp, b);
// each block does 32 channels -> 2 blocks/CU, per-thread FMA halved; o re-read
// is XCD-local L2.
__global__ __launch_bounds__(256) void proj_kernel(const float* __restrict__ o,
                                                   const float* __restrict__ w_proj,
                                                   const float* __restrict__ gamma,
                                                   const float* __restrict__ beta,
                                                   const float* __restrict__ mean,
                                                   const float* __restrict__ var,
                                                   const unsigned char* __restrict__ idx,
                                                   float* __restrict__ out) {
    __shared__ float ws32[64 * 32];                     // my 32 columns of w_proj
    int p = blockIdx.x;
    int b = p & 7, hp = (p >> 3) & 31, half = p >> 8;   // XCD b serves batch b
    int tid = threadIdx.x;
    int ch0 = half * 32;
    for (int i = tid; i < 2048; i += 256)
        ws32[i] = w_proj[(i >> 5) * 64 + ch0 + (i & 31)];
    int wp = tid & 31, cg = tid >> 5;                   // 8 c-groups x 32 wp
    float oreg[64];                                     // my o row in registers
    const float* orow = o + (b * 1024 + hp * 32 + wp) * 64;
    #pragma unroll
    for (int a4 = 0; a4 < 16; a4++) {
        float4 t4 = ((const float4*)orow)[a4];
        oreg[a4 * 4] = t4.x; oreg[a4 * 4 + 1] = t4.y;
        oreg[a4 * 4 + 2] = t4.z; oreg[a4 * 4 + 3] = t4.w;
    }
    __syncthreads();
    {
        int cc0 = cg * 4;                               // my 4 columns within half
        float4 acc = {0.f, 0.f, 0.f, 0.f};
        #pragma unroll
        for (int a = 0; a < 64; a++) {
            float4 wv = *(const float4*)&ws32[a * 32 + cc0];  // 2-addr broadcast
            acc.x += oreg[a] * wv.x; acc.y += oreg[a] * wv.y;
            acc.z += oreg[a] * wv.z; acc.w += oreg[a] * wv.w;
        }
        float accs[4] = { acc.x, acc.y, acc.z, acc.w };
        #pragma unroll
        for (int i = 0; i < 4; i++) {
            int c = ch0 + cc0 + i;
            float inv = gamma[c] * rsqrtf(var[c] + 1e-5f);
            float val = accs[i] * inv + (beta[c] - mean[c] * inv);
            int id = idx[((b * 64 + c) * 32 + hp) * 32 + wp];
            int base = ((b * 64 + c) * 64 + 2 * hp) * 64 + 2 * wp;
            float2 r0 = { id == 0 ? val : 0.f, id == 1 ? val : 0.f };
            float2 r1 = { id == 2 ? val : 0.f, id == 3 ? val : 0.f };
            *(float2*)&out[base] = r0;                  // row 2hp,   cols 2wp..2wp+1
            *(float2*)&out[base + 64] = r1;             // row 2hp+1
        }
    }
}

extern "C" void kernel_launch(void* const* d_in, const int* in_sizes, int n_in,
                              void* d_out, int out_size, void* d_ws, size_t ws_size,
                              hipStream_t stream) {
    const float* x      = (const float*)d_in[0];
    const float* w_qkv  = (const float*)d_in[1];
    const float* w_proj = (const float*)d_in[2];
    const float* gamma  = (const float*)d_in[3];
    const float* beta   = (const float*)d_in[4];
    const float* bn_mean= (const float*)d_in[5];
    const float* bn_var = (const float*)d_in[6];
    float* out = (float*)d_out;

    const int SEG = 524288;                             // 8*1024*64
    float* ws = (float*)d_ws;
    unsigned char* idx = (unsigned char*)(ws + SEG);    // u8 (SEG bytes used)
    float* q   = ws + 2 * SEG;
    float* o   = ws + 5 * SEG;
    uint4*     kg = (uint4*)(ws + 6 * SEG);             // 2 MB
    uint32_tt* vg = (uint32_tt*)(ws + 7 * SEG);         // 1.04 MB

    fused_kernel<<<512, 192, 0, stream>>>(x, w_qkv, q, kg, vg, idx);
    attn_kernel<<<1024, 256, 0, stream>>>(q, kg, vg, o);
    proj_kernel<<<512, 256, 0, stream>>>(o, w_proj, gamma, beta, bn_mean, bn_var, idx, out);
}